// Round 10
// baseline (280.550 us; speedup 1.0000x reference)
//
#include <hip/hip_runtime.h>
#include <stdint.h>

// Problem dims (fixed by reference)
#define BB 4
#define SS 2048
#define EE 512
#define HH 1024
// token rows = 8192, ext rows = 2048

typedef _Float16 f16;
typedef __attribute__((ext_vector_type(8))) _Float16 f16x8;
typedef __attribute__((ext_vector_type(4))) _Float16 f16x4;
typedef __attribute__((ext_vector_type(4))) float f32x4;

__device__ __forceinline__ void async16(void* lds, const void* g) {
  __builtin_amdgcn_global_load_lds(
      (const __attribute__((address_space(1))) unsigned int*)g,
      (__attribute__((address_space(3))) unsigned int*)lds, 16, 0, 0);
}

#define MFMA16 __builtin_amdgcn_mfma_f32_16x16x32_f16

// ---------------------------------------------------------------------------
// Merged prep (R5-verified correct): fp32->fp16 cast of both activations
// (blocks 0..10239) + transpose-split of W into wt_hi/wt_lo (10240..13311).
// ---------------------------------------------------------------------------
__global__ __launch_bounds__(256) void prep_kernel(
    const float* __restrict__ xh32, const float* __restrict__ xe32,
    const float* __restrict__ Wq, const float* __restrict__ Wk,
    const float* __restrict__ Wv,
    f16* __restrict__ xh, f16* __restrict__ xe,
    f16* __restrict__ wt_hi, f16* __restrict__ wt_lo) {
  __shared__ float tile[32][33];
  const int bid = blockIdx.x;
  if (bid < 10240) {  // cast
    const int i = bid * 256 + threadIdx.x;
    const int n4h = 8192 * HH / 4;
    const float* src = i < n4h ? xh32 : xe32;
    f16* dst = i < n4h ? xh : xe;
    const int k = i < n4h ? i : i - n4h;
    const float4 v = ((const float4*)src)[k];
    f16x4 o;
    o.x = (f16)v.x; o.y = (f16)v.y; o.z = (f16)v.z; o.w = (f16)v.w;
    ((f16x4*)dst)[k] = o;
  } else {  // wsplit
    const int b2 = bid - 10240;
    const int k0 = (b2 & 31) * 32;
    const int n0g = (b2 >> 5) * 32;
    const int which = n0g >> 10;
    const float* W = which == 0 ? Wq : (which == 1 ? Wk : Wv);
    const int n0 = n0g & 1023;
    const int tx = threadIdx.x & 31, ty = threadIdx.x >> 5;
#pragma unroll
    for (int i = 0; i < 32; i += 8)
      tile[ty + i][tx] = W[(size_t)(k0 + ty + i) * 1024 + n0 + tx];
    __syncthreads();
#pragma unroll
    for (int i = 0; i < 32; i += 8) {
      const int np = n0g + ty + i;
      const float v = tile[tx][ty + i];
      const size_t idx = (size_t)np * 1024 + k0 + tx;
      const f16 h = (f16)v;
      wt_hi[idx] = h;
      wt_lo[idx] = (f16)(v - (float)h);
    }
  }
}

// ---------------------------------------------------------------------------
// Projection GEMM, 256x256 tile, 8-phase counted-vmcnt schedule.
// R10 CHANGE: phase MFMA partition split by i (M-half) instead of j:
//   ph0 reads a[0..3]+b[0..3] (8 ds_reads), MFMA i0-3 x j0-3;
//   ph1 reads a[4..7] (4 ds_reads, b reused), MFMA i4-7 x j0-3.
// This matches m201's 8/4 read cadence (was 10/2 with the by-j split) and
// shortens the lgkm chain in front of each MFMA cluster. Staging calls,
// vmcnt ledger (verified identical), swizzle, epilogue, grid: unchanged.
// Structural pins: 1 block/CU (128KB LDS); acc[8][4] forbids tighter
// launch_bounds (R5 spill); 256^2 tile required for reuse (R3); grid at the
// 3-work-unit makespan bound (608 units / 256 CUs, heavy=2 indivisible).
// ---------------------------------------------------------------------------
__global__ __launch_bounds__(512, 2) void proj_kernel(
    const f16* __restrict__ xh, const f16* __restrict__ xe,
    const f16* __restrict__ wt_hi, const f16* __restrict__ wt_lo,
    const float* __restrict__ bq, const float* __restrict__ bk,
    const float* __restrict__ bv, f16* __restrict__ q_hi, f16* __restrict__ q_lo,
    f16* __restrict__ kt, f16* __restrict__ vt,
    f16* __restrict__ ke_hi, f16* __restrict__ ke_lo, f16* __restrict__ veT) {
  const int g = blockIdx.x;
  const int j = g & 7;   // XCD (round-robin assumption)
  const int s = g >> 3;  // 0..55
  int mrow0, colB0;
  bool ext = false, splitB = false;
  if (s < 20) {  // heavy segment, NT=32
    splitB = true;
    if (s < 16) {  // token q
      colB0 = (s >> 2) * 256;
      mrow0 = ((s & 3) * 8 + j) * 256;
    } else {  // ext ke
      ext = true;
      colB0 = 1024 + (s - 16) * 256;
      mrow0 = j * 256;
    }
  } else {  // light segment, NT=16
    const int s2 = s - 20;
    if (s2 < 32) {  // token k,v
      colB0 = (4 + (s2 >> 2)) * 256;
      mrow0 = ((s2 & 3) * 8 + j) * 256;
    } else {  // ext v
      ext = true;
      colB0 = 1024 + (4 + (s2 - 32)) * 256;
      mrow0 = j * 256;
    }
  }
  const int NT = splitB ? 32 : 16;

  __shared__ f16 lds[65536];  // 128 KiB

  const int tid = threadIdx.x;
  const int wave = tid >> 6, lane = tid & 63;
  const int wm = wave >> 2, wn = wave & 3;
  const int frow = lane & 15, qd = lane >> 4;

  const f16* A0 = (ext ? xe : xh) + (size_t)mrow0 * HH;
  const f16* Bhi = wt_hi + (size_t)colB0 * HH;
  const f16* Blo = wt_lo + (size_t)colB0 * HH;

  const int srow = tid >> 2;
  const int scol = ((tid & 3) ^ ((srow >> 1) & 3)) * 8;
  const size_t gO0 = (size_t)srow * HH + scol;
  const size_t gO1 = (size_t)(128 + srow) * HH + scol;
  const int ldst0 = (wave * 64) * 8;
  const int ldst1 = (512 + wave * 64) * 8;

  int offA[8], offB[4];
#pragma unroll
  for (int i = 0; i < 8; ++i) {
    const int r = wm * 128 + i * 16 + frow;
    offA[i] = r * 32 + ((qd ^ ((r >> 1) & 3)) * 8);
  }
#pragma unroll
  for (int jj = 0; jj < 4; ++jj) {
    const int r = wn * 64 + jj * 16 + frow;
    offB[jj] = r * 32 + ((qd ^ ((r >> 1) & 3)) * 8);
  }

  f32x4 acc[8][4];
#pragma unroll
  for (int i = 0; i < 8; ++i)
#pragma unroll
    for (int jj = 0; jj < 4; ++jj)
#pragma unroll
      for (int r = 0; r < 4; ++r) acc[i][jj][r] = 0.0f;

  {
    f16* dA0 = &lds[0];
    f16* dB0 = &lds[32768];
    f16* dA1 = &lds[8192];
    f16* dB1 = &lds[32768 + 8192];
    async16(&dA0[ldst0], A0 + gO0);       async16(&dA0[ldst1], A0 + gO1);
    async16(&dB0[ldst0], Bhi + gO0);      async16(&dB0[ldst1], Bhi + gO1);
    async16(&dA1[ldst0], A0 + 32 + gO0);  async16(&dA1[ldst1], A0 + 32 + gO1);
    async16(&dB1[ldst0], Bhi + 32 + gO0); async16(&dB1[ldst1], Bhi + 32 + gO1);
  }
  asm volatile("s_waitcnt vmcnt(4)" ::: "memory");
  __builtin_amdgcn_s_barrier();

  for (int t = 0; t < NT; ++t) {
    const int cur = t & 1, nxt = cur ^ 1;
    const bool st = (t + 1 < NT);
    const int kn = ((t + 1) & 15) * 64;
    const f16* An = A0 + kn;
    const f16* Bn = (((t + 1) & 16) ? Blo : Bhi) + kn;
    const f16* lA0 = &lds[(cur * 2 + 0) * 8192];
    const f16* lB0 = &lds[32768 + (cur * 2 + 0) * 8192];
    const f16* lA1 = &lds[(cur * 2 + 1) * 8192];
    const f16* lB1 = &lds[32768 + (cur * 2 + 1) * 8192];
    f16* sA0 = &lds[(nxt * 2 + 0) * 8192];
    f16* sB0 = &lds[32768 + (nxt * 2 + 0) * 8192];
    f16* sA1 = &lds[(nxt * 2 + 1) * 8192];
    f16* sB1 = &lds[32768 + (nxt * 2 + 1) * 8192];

    f16x8 a[4], b[4];

    // ---- phase 0: kh0, read a[0..3]+b[0..3] (8 reads); stage Ak0(t+1)
#pragma unroll
    for (int i = 0; i < 4; ++i) a[i] = *(const f16x8*)&lA0[offA[i]];
#pragma unroll
    for (int jj = 0; jj < 4; ++jj) b[jj] = *(const f16x8*)&lB0[offB[jj]];
    if (st) { async16(&sA0[ldst0], An + gO0); async16(&sA0[ldst1], An + gO1); }
    __builtin_amdgcn_s_barrier();
    __builtin_amdgcn_s_setprio(1);
#pragma unroll
    for (int i = 0; i < 4; ++i)
#pragma unroll
      for (int jj = 0; jj < 4; ++jj)
        acc[i][jj] = MFMA16(a[i], b[jj], acc[i][jj], 0, 0, 0);
    __builtin_amdgcn_s_setprio(0);
    __builtin_amdgcn_s_barrier();

    // ---- phase 1: kh0, read a[4..7] (4 reads, b reused); stage Bk0(t+1)
#pragma unroll
    for (int i = 0; i < 4; ++i) a[i] = *(const f16x8*)&lA0[offA[4 + i]];
    if (st) { async16(&sB0[ldst0], Bn + gO0); async16(&sB0[ldst1], Bn + gO1); }
    __builtin_amdgcn_s_barrier();
    __builtin_amdgcn_s_setprio(1);
#pragma unroll
    for (int i = 0; i < 4; ++i)
#pragma unroll
      for (int jj = 0; jj < 4; ++jj)
        acc[4 + i][jj] = MFMA16(a[i], b[jj], acc[4 + i][jj], 0, 0, 0);
    __builtin_amdgcn_s_setprio(0);
    if (t == NT - 1) {
      asm volatile("s_waitcnt vmcnt(0)" ::: "memory");
    } else {
      asm volatile("s_waitcnt vmcnt(4)" ::: "memory");  // Ak1,Bk1(t) landed
    }
    __builtin_amdgcn_s_barrier();

    // ---- phase 2: kh1, read a[0..3]+b[0..3]; stage Ak1(t+1)
#pragma unroll
    for (int i = 0; i < 4; ++i) a[i] = *(const f16x8*)&lA1[offA[i]];
#pragma unroll
    for (int jj = 0; jj < 4; ++jj) b[jj] = *(const f16x8*)&lB1[offB[jj]];
    if (st) { async16(&sA1[ldst0], An + 32 + gO0); async16(&sA1[ldst1], An + 32 + gO1); }
    __builtin_amdgcn_s_barrier();
    __builtin_amdgcn_s_setprio(1);
#pragma unroll
    for (int i = 0; i < 4; ++i)
#pragma unroll
      for (int jj = 0; jj < 4; ++jj)
        acc[i][jj] = MFMA16(a[i], b[jj], acc[i][jj], 0, 0, 0);
    __builtin_amdgcn_s_setprio(0);
    __builtin_amdgcn_s_barrier();

    // ---- phase 3: kh1, read a[4..7]; stage Bk1(t+1)
#pragma unroll
    for (int i = 0; i < 4; ++i) a[i] = *(const f16x8*)&lA1[offA[4 + i]];
    if (st) { async16(&sB1[ldst0], Bn + 32 + gO0); async16(&sB1[ldst1], Bn + 32 + gO1); }
    __builtin_amdgcn_s_barrier();
    __builtin_amdgcn_s_setprio(1);
#pragma unroll
    for (int i = 0; i < 4; ++i)
#pragma unroll
      for (int jj = 0; jj < 4; ++jj)
        acc[4 + i][jj] = MFMA16(a[i], b[jj], acc[4 + i][jj], 0, 0, 0);
    __builtin_amdgcn_s_setprio(0);
    asm volatile("s_waitcnt vmcnt(4)" ::: "memory");  // Ak0,Bk0(t+1) landed
    __builtin_amdgcn_s_barrier();
  }

  // -------------------- epilogue --------------------
  const int er0 = wm * 128 + qd * 4;
  const int ec0 = wn * 64 + frow;
  float bias[4];
#pragma unroll
  for (int jj = 0; jj < 4; ++jj) {
    const int c = colB0 + ec0 + jj * 16;
    bias[jj] = c < 1024 ? bq[c] : (c < 2048 ? bk[c - 1024] : bv[c - 2048]);
  }

  if (!ext) {
    if (colB0 < 1024) {  // q: hi+lo
#pragma unroll
      for (int jj = 0; jj < 4; ++jj) {
        const int c = colB0 + ec0 + jj * 16;
#pragma unroll
        for (int i = 0; i < 8; ++i)
#pragma unroll
          for (int r = 0; r < 4; ++r) {
            const int row = mrow0 + er0 + i * 16 + r;
            const float val = acc[i][jj][r] + bias[jj];
            const size_t idx = (size_t)row * HH + c;
            const f16 h = (f16)val;
            q_hi[idx] = h;
            q_lo[idx] = (f16)(val - (float)h);
          }
      }
    } else if (colB0 < 2048) {  // token k
#pragma unroll
      for (int jj = 0; jj < 4; ++jj) {
        const int c = colB0 + ec0 + jj * 16 - 1024;
#pragma unroll
        for (int i = 0; i < 8; ++i)
#pragma unroll
          for (int r = 0; r < 4; ++r) {
            const int row = mrow0 + er0 + i * 16 + r;
            kt[(size_t)row * HH + c] = (f16)(acc[i][jj][r] + bias[jj]);
          }
      }
    } else {  // token v
#pragma unroll
      for (int jj = 0; jj < 4; ++jj) {
        const int c = colB0 + ec0 + jj * 16 - 2048;
#pragma unroll
        for (int i = 0; i < 8; ++i)
#pragma unroll
          for (int r = 0; r < 4; ++r) {
            const int row = mrow0 + er0 + i * 16 + r;
            vt[(size_t)row * HH + c] = (f16)(acc[i][jj][r] + bias[jj]);
          }
      }
    }
  } else {
    if (colB0 < 2048) {  // ext k: hi+lo
#pragma unroll
      for (int jj = 0; jj < 4; ++jj) {
        const int c = colB0 + ec0 + jj * 16 - 1024;
#pragma unroll
        for (int i = 0; i < 8; ++i)
#pragma unroll
          for (int r = 0; r < 4; ++r) {
            const int row = mrow0 + er0 + i * 16 + r;
            const float val = acc[i][jj][r] + bias[jj];
            const size_t idx = (size_t)row * HH + c;
            const f16 h = (f16)val;
            ke_hi[idx] = h;
            ke_lo[idx] = (f16)(val - (float)h);
          }
      }
    } else {  // ext v -> veT[b][h][e], transposed via LDS in two h-halves
      f16* tl = lds;  // [128][264]
      const int b = mrow0 >> 9, e0 = mrow0 & 511;
      const int h0 = colB0 - 2048;
#pragma unroll
      for (int p = 0; p < 2; ++p) {
        __syncthreads();
        if ((wn >> 1) == p) {
          const int hL = (wn & 1) * 64 + frow;
#pragma unroll
          for (int jj = 0; jj < 4; ++jj)
#pragma unroll
            for (int i = 0; i < 8; ++i)
#pragma unroll
              for (int r = 0; r < 4; ++r) {
                const int e = er0 + i * 16 + r;
                tl[(hL + jj * 16) * 264 + e] = (f16)(acc[i][jj][r] + bias[jj]);
              }
        }
        __syncthreads();
        for (int c = tid; c < 128 * 32; c += 512) {
          const int hL = c >> 5, ch = c & 31;
          const f16x8 v = *(const f16x8*)&tl[hL * 264 + ch * 8];
          *(f16x8*)&veT[(size_t)(b * HH + h0 + p * 128 + hL) * EE + e0 + ch * 8] = v;
        }
      }
    }
  }
}

// ---------------------------------------------------------------------------
// Score GEMM (R7 config): 256x128, K=512, triple-buffer depth-2, one barrier
// + counted vmcnt per k-step.
// ---------------------------------------------------------------------------
__global__ __launch_bounds__(512, 1) void score_kernel(
    const f16* __restrict__ q_hi, const f16* __restrict__ q_lo,
    const f16* __restrict__ ke_hi, const f16* __restrict__ ke_lo,
    float* __restrict__ s_part) {
  const int b = blockIdx.z & 3;
  const int khalf = blockIdx.z >> 2;
  const int mtile = blockIdx.y;  // 0..7 (256 rows of s)
  const int ntile = blockIdx.x;  // 0..3 (128 cols of e)

  __shared__ f16 lds[73728];  // 144 KB

  const int tid = threadIdx.x;
  const int wave = tid >> 6, lane = tid & 63;
  const int wm = wave >> 1, wn = wave & 1;
  const int frow = lane & 15, qd = lane >> 4;

  const size_t aoff = ((size_t)b * SS + mtile * 256) * HH + khalf * 512;
  const size_t boff = ((size_t)b * EE + ntile * 128) * HH + khalf * 512;
  const f16* Ah = q_hi + aoff;
  const f16* Al = q_lo + aoff;
  const f16* Bh = ke_hi + boff;
  const f16* Bl = ke_lo + boff;

  const int srow = tid >> 2;
  const int scol = ((tid & 3) ^ ((srow >> 1) & 3)) * 8;
  const size_t gA0 = (size_t)srow * HH + scol;
  const size_t gA1 = (size_t)(128 + srow) * HH + scol;
  const int ldstA0 = (wave * 64) * 8;
  const int ldstA1 = (512 + wave * 64) * 8;
  const int ldstB0 = (wave * 64) * 8;

  int offA[4], offB[4];
#pragma unroll
  for (int i = 0; i < 4; ++i) {
    const int r = wm * 64 + i * 16 + frow;
    offA[i] = r * 32 + ((qd ^ ((r >> 1) & 3)) * 8);
  }
#pragma unroll
  for (int jj = 0; jj < 4; ++jj) {
    const int r = wn * 64 + jj * 16 + frow;
    offB[jj] = r * 32 + ((qd ^ ((r >> 1) & 3)) * 8);
  }

  f32x4 acc[4][4];
#pragma unroll
  for (int i = 0; i < 4; ++i)
#pragma unroll
    for (int jj = 0; jj < 4; ++jj)
#pragma unroll
      for (int r = 0; r < 4; ++r) acc[i][jj][r] = 0.0f;

  // Prologue: stage step 0 -> buf0 and step 1 -> buf1 (6 loads each)
#pragma unroll
  for (int p = 0; p < 2; ++p) {
    f16* dAh = &lds[p * 24576];
    f16* dAl = &lds[p * 24576 + 8192];
    f16* dBh = &lds[p * 24576 + 16384];
    f16* dBl = &lds[p * 24576 + 20480];
    const int ko = p * 32;
    async16(&dAh[ldstA0], Ah + ko + gA0); async16(&dAh[ldstA1], Ah + ko + gA1);
    async16(&dBh[ldstB0], Bh + ko + gA0);
    async16(&dBl[ldstB0], Bl + ko + gA0);
    async16(&dAl[ldstA0], Al + ko + gA0); async16(&dAl[ldstA1], Al + ko + gA1);
  }
  asm volatile("s_waitcnt vmcnt(6)" ::: "memory");  // step 0's 6 landed
  __builtin_amdgcn_s_barrier();

  int cur = 0, stg = 2;
  for (int t = 0; t < 16; ++t) {
    const bool st = (t < 14);
    const int kk = (t + 2) * 32;
    const f16* lAh = &lds[cur * 24576];
    const f16* lAl = &lds[cur * 24576 + 8192];
    const f16* lBh = &lds[cur * 24576 + 16384];
    const f16* lBl = &lds[cur * 24576 + 20480];

    // stage step t+2 (6 loads) into buf stg — last read ended 2 barriers ago
    if (st) {
      f16* sAh = &lds[stg * 24576];
      f16* sAl = &lds[stg * 24576 + 8192];
      f16* sBh = &lds[stg * 24576 + 16384];
      f16* sBl = &lds[stg * 24576 + 20480];
      async16(&sAh[ldstA0], Ah + kk + gA0); async16(&sAh[ldstA1], Ah + kk + gA1);
      async16(&sBh[ldstB0], Bh + kk + gA0);
      async16(&sBl[ldstB0], Bl + kk + gA0);
      async16(&sAl[ldstA0], Al + kk + gA0); async16(&sAl[ldstA1], Al + kk + gA1);
    }

    f16x8 ah[4], bh[4], bl[4], al[4];
#pragma unroll
    for (int i = 0; i < 4; ++i) ah[i] = *(const f16x8*)&lAh[offA[i]];
#pragma unroll
    for (int jj = 0; jj < 4; ++jj) bh[jj] = *(const f16x8*)&lBh[offB[jj]];
#pragma unroll
    for (int jj = 0; jj < 4; ++jj) bl[jj] = *(const f16x8*)&lBl[offB[jj]];
#pragma unroll
    for (int i = 0; i < 4; ++i) al[i] = *(const f16x8*)&lAl[offA[i]];

    __builtin_amdgcn_s_setprio(1);
#pragma unroll
    for (int i = 0; i < 4; ++i)
#pragma unroll
      for (int jj = 0; jj < 4; ++jj) {
        acc[i][jj] = MFMA16(ah[i], bh[jj], acc[i][jj], 0, 0, 0);
        acc[i][jj] = MFMA16(ah[i], bl[jj], acc[i][jj], 0, 0, 0);
        acc[i][jj] = MFMA16(al[i], bh[jj], acc[i][jj], 0, 0, 0);
      }
    __builtin_amdgcn_s_setprio(0);

    if (st) { asm volatile("s_waitcnt vmcnt(6)" ::: "memory"); }  // t+1 landed
    else    { asm volatile("s_waitcnt vmcnt(0)" ::: "memory"); }
    __builtin_amdgcn_s_barrier();

    cur = (cur == 2) ? 0 : cur + 1;
    stg = (stg == 2) ? 0 : stg + 1;
  }

  // epilogue: scalar f32 stores
  float* dst = s_part + (size_t)khalf * BB * SS * EE + (size_t)b * SS * EE;
#pragma unroll
  for (int jj = 0; jj < 4; ++jj) {
    const int e = ntile * 128 + wn * 64 + jj * 16 + frow;
#pragma unroll
    for (int i = 0; i < 4; ++i)
#pragma unroll
      for (int r = 0; r < 4; ++r) {
        const int s = mtile * 256 + wm * 64 + i * 16 + qd * 4 + r;
        dst[(size_t)s * EE + e] = acc[i][jj][r];
      }
  }
}

// Fused selfdot + softmax (unchanged)
__global__ __launch_bounds__(256) void softmax_kernel(
    const f16* __restrict__ q_hi, const f16* __restrict__ q_lo,
    const f16* __restrict__ kt, const float* __restrict__ s_part,
    f16* __restrict__ probs, float* __restrict__ p_self) {
  const int t = blockIdx.x * 4 + (threadIdx.x >> 6);
  const int lane = threadIdx.x & 63;

  const size_t base = (size_t)t * HH;
  float ss = 0.f;
#pragma unroll
  for (int it = 0; it < 4; ++it) {
    const int off = it * 256 + lane * 4;
    const f16x4 qh = *(const f16x4*)&q_hi[base + off];
    const f16x4 ql = *(const f16x4*)&q_lo[base + off];
    const f16x4 kh = *(const f16x4*)&kt[base + off];
    ss += ((float)qh.x + (float)ql.x) * (float)kh.x;
    ss += ((float)qh.y + (float)ql.y) * (float)kh.y;
    ss += ((float)qh.z + (float)ql.z) * (float)kh.z;
    ss += ((float)qh.w + (float)ql.w) * (float)kh.w;
  }
#pragma unroll
  for (int m = 32; m > 0; m >>= 1) ss += __shfl_xor(ss, m, 64);

  const float* r0 = s_part + (size_t)t * EE;
  const float* r1 = s_part + (size_t)BB * SS * EE + (size_t)t * EE;
  const float4 a0 = *(const float4*)&r0[lane * 4];
  const float4 a1 = *(const float4*)&r0[256 + lane * 4];
  const float4 c0 = *(const float4*)&r1[lane * 4];
  const float4 c1 = *(const float4*)&r1[256 + lane * 4];
  const float v0x = a0.x + c0.x, v0y = a0.y + c0.y, v0z = a0.z + c0.z, v0w = a0.w + c0.w;
  const float v1x = a1.x + c1.x, v1y = a1.y + c1.y, v1z = a1.z + c1.z, v1w = a1.w + c1.w;
  float m = fmaxf(fmaxf(fmaxf(v0x, v0y), fmaxf(v0z, v0w)),
                  fmaxf(fmaxf(v1x, v1y), fmaxf(v1z, v1w)));
#pragma unroll
  for (int sh = 32; sh > 0; sh >>= 1) m = fmaxf(m, __shfl_xor(m, sh, 64));
  m = fmaxf(m, ss);
  const float e0 = __expf(v0x - m), e1 = __expf(v0y - m);
  const float e2 = __expf(v0z - m), e3 = __expf(v0w - m);
  const float e4 = __expf(v1x - m), e5 = __expf(v1y - m);
  const float e6 = __expf(v1z - m), e7 = __expf(v1w - m);
  float sum = ((e0 + e1) + (e2 + e3)) + ((e4 + e5) + (e6 + e7));
#pragma unroll
  for (int sh = 32; sh > 0; sh >>= 1) sum += __shfl_xor(sum, sh, 64);
  const float es = __expf(ss - m);
  const float inv = 1.0f / (sum + es);
  f16x4 p0, p1;
  p0.x = (f16)(e0 * inv); p0.y = (f16)(e1 * inv);
  p0.z = (f16)(e2 * inv); p0.w = (f16)(e3 * inv);
  p1.x = (f16)(e4 * inv); p1.y = (f16)(e5 * inv);
  p1.z = (f16)(e6 * inv); p1.w = (f16)(e7 * inv);
  *(f16x4*)&probs[(size_t)t * EE + lane * 4] = p0;
  *(f16x4*)&probs[(size_t)t * EE + 256 + lane * 4] = p1;
  if (lane == 0) p_self[t] = es * inv;
}

// ---------------------------------------------------------------------------
// PV GEMM (R7 1-barrier version): 256x128, K=512, triple-buffer depth-2,
// one barrier + counted vmcnt per k-step.
// ---------------------------------------------------------------------------
__global__ __launch_bounds__(512, 2) void pv_kernel(
    const f16* __restrict__ probs, const f16* __restrict__ veT,
    const float* __restrict__ p_self, const f16* __restrict__ vt,
    float* __restrict__ out) {
  const int b = blockIdx.z;
  const int mtile = blockIdx.y;  // 0..7 (256 rows of s)
  const int ntile = blockIdx.x;  // 0..7 (128 cols of h)

  __shared__ f16 lds[36864];  // 72 KB: 3 x (A 8192 | B 4096)

  const int tid = threadIdx.x;
  const int wave = tid >> 6, lane = tid & 63;
  const int wm = wave >> 1, wn = wave & 1;
  const int frow = lane & 15, qd = lane >> 4;

  const size_t aoff = ((size_t)b * SS + mtile * 256) * EE;
  const size_t boff = ((size_t)b * HH + ntile * 128) * EE;
  const f16* A = probs + aoff;
  const f16* Bv = veT + boff;

  const int srow = tid >> 2;
  const int scol = ((tid & 3) ^ ((srow >> 1) & 3)) * 8;
  const size_t gA0 = (size_t)srow * EE + scol;
  const size_t gA1 = (size_t)(128 + srow) * EE + scol;
  const int ldstA0 = (wave * 64) * 8;
  const int ldstA1 = (512 + wave * 64) * 8;
  const int ldstB0 = (wave * 64) * 8;

  int offA[4], offB[4];
#pragma unroll
  for (int i = 0; i < 4; ++i) {
    const int r = wm * 64 + i * 16 + frow;
    offA[i] = r * 32 + ((qd ^ ((r >> 1) & 3)) * 8);
  }
#pragma unroll
  for (int jj = 0; jj < 4; ++jj) {
    const int r = wn * 64 + jj * 16 + frow;
    offB[jj] = r * 32 + ((qd ^ ((r >> 1) & 3)) * 8);
  }

  f32x4 acc[4][4];
#pragma unroll
  for (int i = 0; i < 4; ++i)
#pragma unroll
    for (int jj = 0; jj < 4; ++jj)
#pragma unroll
      for (int r = 0; r < 4; ++r) acc[i][jj][r] = 0.0f;

  {
    f16* dA0 = &lds[0], *dB0 = &lds[8192];
    f16* dA1 = &lds[12288], *dB1 = &lds[12288 + 8192];
    async16(&dA0[ldstA0], A + gA0); async16(&dA0[ldstA1], A + gA1);
    async16(&dB0[ldstB0], Bv + gA0);
    async16(&dA1[ldstA0], A + 32 + gA0); async16(&dA1[ldstA1], A + 32 + gA1);
    async16(&dB1[ldstB0], Bv + 32 + gA0);
  }
  asm volatile("s_waitcnt vmcnt(3)" ::: "memory");
  __builtin_amdgcn_s_barrier();

  int cur = 0, stg = 2;
  for (int t = 0; t < 16; ++t) {
    const bool st = (t < 14);
    const int kk = (t + 2) * 32;
    const f16* lA = &lds[cur * 12288];
    const f16* lB = &lds[cur * 12288 + 8192];

    if (st) {
      f16* sA = &lds[stg * 12288];
      f16* sB = &lds[stg * 12288 + 8192];
      async16(&sA[ldstA0], A + kk + gA0); async16(&sA[ldstA1], A + kk + gA1);
      async16(&sB[ldstB0], Bv + kk + gA0);
    }

    f16x8 a[4], bb[4];
#pragma unroll
    for (int i = 0; i < 4; ++i) a[i] = *(const f16x8*)&lA[offA[i]];
#pragma unroll
    for (int jj = 0; jj < 4; ++jj) bb[jj] = *(const f16x8*)&lB[offB[jj]];

    __builtin_amdgcn_s_setprio(1);
#pragma unroll
    for (int i = 0; i < 4; ++i)
#pragma unroll
      for (int jj = 0; jj < 4; ++jj)
        acc[i][jj] = MFMA16(a[i], bb[jj], acc[i][jj], 0, 0, 0);
    __builtin_amdgcn_s_setprio(0);

    if (st) { asm volatile("s_waitcnt vmcnt(3)" ::: "memory"); }
    else    { asm volatile("s_waitcnt vmcnt(0)" ::: "memory"); }
    __builtin_amdgcn_s_barrier();

    cur = (cur == 2) ? 0 : cur + 1;
    stg = (stg == 2) ? 0 : stg + 1;
  }

  // epilogue
#pragma unroll
  for (int jj = 0; jj < 4; ++jj) {
    const int h = ntile * 128 + wn * 64 + jj * 16 + frow;
#pragma unroll
    for (int i = 0; i < 4; ++i)
#pragma unroll
      for (int r = 0; r < 4; ++r) {
        const int s = mtile * 256 + wm * 64 + i * 16 + qd * 4 + r;
        const size_t t = (size_t)b * SS + s;
        __builtin_nontemporal_store(
            acc[i][jj][r] + p_self[t] * (float)vt[t * HH + h], &out[t * HH + h]);
      }
  }
}

extern "C" void kernel_launch(void* const* d_in, const int* in_sizes, int n_in,
                              void* d_out, int out_size, void* d_ws, size_t ws_size,
                              hipStream_t stream) {
  const float* hidden = (const float*)d_in[0];
  const float* ext    = (const float*)d_in[1];
  const float* Wq = (const float*)d_in[2];
  const float* bq = (const float*)d_in[3];
  const float* Wk = (const float*)d_in[4];
  const float* bk = (const float*)d_in[5];
  const float* Wv = (const float*)d_in[6];
  const float* bv = (const float*)d_in[7];
  float* out = (float*)d_out;

  char* ws = (char*)d_ws;
  size_t off = 0;
  auto alloc = [&](size_t bytes) {
    char* p = ws + off;
    off += (bytes + 255) & ~(size_t)255;
    return p;
  };
  const size_t TOK = 8192, EXT = 2048;
  f16* xh    = (f16*)alloc(TOK * HH * 2);
  f16* xe    = (f16*)alloc(EXT * HH * 2);
  f16* wt_hi = (f16*)alloc(3072ull * HH * 2);
  f16* wt_lo = (f16*)alloc(3072ull * HH * 2);
  f16* q_hi  = (f16*)alloc(TOK * HH * 2);
  f16* q_lo  = (f16*)alloc(TOK * HH * 2);
  f16* kt    = (f16*)alloc(TOK * HH * 2);
  f16* vt    = (f16*)alloc(TOK * HH * 2);
  f16* ke_hi = (f16*)alloc(EXT * HH * 2);
  f16* ke_lo = (f16*)alloc(EXT * HH * 2);
  f16* veT   = (f16*)alloc((size_t)BB * HH * EE * 2);
  float* p_self = (float*)alloc(TOK * 4);
  float* s_part = (float*)alloc(2ull * BB * SS * EE * 4);
  f16* probs    = (f16*)alloc((size_t)BB * SS * EE * 2);

  // 1. merged prep: cast + W transpose/split in one launch
  prep_kernel<<<13312, 256, 0, stream>>>(hidden, ext, Wq, Wk, Wv,
                                         xh, xe, wt_hi, wt_lo);

  // 2. fused projection GEMM, 256^2, balanced 8/4-read phases (R10)
  proj_kernel<<<448, 512, 0, stream>>>(
      xh, xe, wt_hi, wt_lo, bq, bk, bv,
      q_hi, q_lo, kt, vt, ke_hi, ke_lo, veT);

  // 3. attention
  score_kernel<<<dim3(4, 8, 8), 512, 0, stream>>>(q_hi, q_lo, ke_hi, ke_lo, s_part);
  softmax_kernel<<<2048, 256, 0, stream>>>(q_hi, q_lo, kt, s_part, probs, p_self);
  pv_kernel<<<dim3(8, 8, 4), 512, 0, stream>>>(probs, veT, p_self, vt, out);
}

// Round 11
// 274.714 us; speedup vs baseline: 1.0212x; 1.0212x over previous
//
#include <hip/hip_runtime.h>
#include <stdint.h>

// Problem dims (fixed by reference)
#define BB 4
#define SS 2048
#define EE 512
#define HH 1024
// token rows = 8192, ext rows = 2048

typedef _Float16 f16;
typedef __attribute__((ext_vector_type(8))) _Float16 f16x8;
typedef __attribute__((ext_vector_type(4))) _Float16 f16x4;
typedef __attribute__((ext_vector_type(4))) float f32x4;

__device__ __forceinline__ void async16(void* lds, const void* g) {
  __builtin_amdgcn_global_load_lds(
      (const __attribute__((address_space(1))) unsigned int*)g,
      (__attribute__((address_space(3))) unsigned int*)lds, 16, 0, 0);
}

#define MFMA16 __builtin_amdgcn_mfma_f32_16x16x32_f16

// ---------------------------------------------------------------------------
// Merged prep (R5-verified correct): fp32->fp16 cast of both activations
// (blocks 0..10239) + transpose-split of W into wt_hi/wt_lo (10240..13311).
// ---------------------------------------------------------------------------
__global__ __launch_bounds__(256) void prep_kernel(
    const float* __restrict__ xh32, const float* __restrict__ xe32,
    const float* __restrict__ Wq, const float* __restrict__ Wk,
    const float* __restrict__ Wv,
    f16* __restrict__ xh, f16* __restrict__ xe,
    f16* __restrict__ wt_hi, f16* __restrict__ wt_lo) {
  __shared__ float tile[32][33];
  const int bid = blockIdx.x;
  if (bid < 10240) {  // cast
    const int i = bid * 256 + threadIdx.x;
    const int n4h = 8192 * HH / 4;
    const float* src = i < n4h ? xh32 : xe32;
    f16* dst = i < n4h ? xh : xe;
    const int k = i < n4h ? i : i - n4h;
    const float4 v = ((const float4*)src)[k];
    f16x4 o;
    o.x = (f16)v.x; o.y = (f16)v.y; o.z = (f16)v.z; o.w = (f16)v.w;
    ((f16x4*)dst)[k] = o;
  } else {  // wsplit
    const int b2 = bid - 10240;
    const int k0 = (b2 & 31) * 32;
    const int n0g = (b2 >> 5) * 32;
    const int which = n0g >> 10;
    const float* W = which == 0 ? Wq : (which == 1 ? Wk : Wv);
    const int n0 = n0g & 1023;
    const int tx = threadIdx.x & 31, ty = threadIdx.x >> 5;
#pragma unroll
    for (int i = 0; i < 32; i += 8)
      tile[ty + i][tx] = W[(size_t)(k0 + ty + i) * 1024 + n0 + tx];
    __syncthreads();
#pragma unroll
    for (int i = 0; i < 32; i += 8) {
      const int np = n0g + ty + i;
      const float v = tile[tx][ty + i];
      const size_t idx = (size_t)np * 1024 + k0 + tx;
      const f16 h = (f16)v;
      wt_hi[idx] = h;
      wt_lo[idx] = (f16)(v - (float)h);
    }
  }
}

// ---------------------------------------------------------------------------
// Projection GEMM, 256x256 tile, 8-phase counted-vmcnt schedule (R10 by-i
// phase split kept: 109-111us, MfmaUtil 30.9%). Structural pins: 1 block/CU
// (128KB LDS); acc[8][4] forbids tighter launch_bounds (R5 spill); 256^2 tile
// required for reuse (R3); grid at 3-unit makespan bound. Six schedule probes
// flat -> pinned at ~110us for this toolkit.
// ---------------------------------------------------------------------------
__global__ __launch_bounds__(512, 2) void proj_kernel(
    const f16* __restrict__ xh, const f16* __restrict__ xe,
    const f16* __restrict__ wt_hi, const f16* __restrict__ wt_lo,
    const float* __restrict__ bq, const float* __restrict__ bk,
    const float* __restrict__ bv, f16* __restrict__ q_hi, f16* __restrict__ q_lo,
    f16* __restrict__ kt, f16* __restrict__ vt,
    f16* __restrict__ ke_hi, f16* __restrict__ ke_lo, f16* __restrict__ veT) {
  const int g = blockIdx.x;
  const int j = g & 7;   // XCD (round-robin assumption)
  const int s = g >> 3;  // 0..55
  int mrow0, colB0;
  bool ext = false, splitB = false;
  if (s < 20) {  // heavy segment, NT=32
    splitB = true;
    if (s < 16) {  // token q
      colB0 = (s >> 2) * 256;
      mrow0 = ((s & 3) * 8 + j) * 256;
    } else {  // ext ke
      ext = true;
      colB0 = 1024 + (s - 16) * 256;
      mrow0 = j * 256;
    }
  } else {  // light segment, NT=16
    const int s2 = s - 20;
    if (s2 < 32) {  // token k,v
      colB0 = (4 + (s2 >> 2)) * 256;
      mrow0 = ((s2 & 3) * 8 + j) * 256;
    } else {  // ext v
      ext = true;
      colB0 = 1024 + (4 + (s2 - 32)) * 256;
      mrow0 = j * 256;
    }
  }
  const int NT = splitB ? 32 : 16;

  __shared__ f16 lds[65536];  // 128 KiB

  const int tid = threadIdx.x;
  const int wave = tid >> 6, lane = tid & 63;
  const int wm = wave >> 2, wn = wave & 3;
  const int frow = lane & 15, qd = lane >> 4;

  const f16* A0 = (ext ? xe : xh) + (size_t)mrow0 * HH;
  const f16* Bhi = wt_hi + (size_t)colB0 * HH;
  const f16* Blo = wt_lo + (size_t)colB0 * HH;

  const int srow = tid >> 2;
  const int scol = ((tid & 3) ^ ((srow >> 1) & 3)) * 8;
  const size_t gO0 = (size_t)srow * HH + scol;
  const size_t gO1 = (size_t)(128 + srow) * HH + scol;
  const int ldst0 = (wave * 64) * 8;
  const int ldst1 = (512 + wave * 64) * 8;

  int offA[8], offB[4];
#pragma unroll
  for (int i = 0; i < 8; ++i) {
    const int r = wm * 128 + i * 16 + frow;
    offA[i] = r * 32 + ((qd ^ ((r >> 1) & 3)) * 8);
  }
#pragma unroll
  for (int jj = 0; jj < 4; ++jj) {
    const int r = wn * 64 + jj * 16 + frow;
    offB[jj] = r * 32 + ((qd ^ ((r >> 1) & 3)) * 8);
  }

  f32x4 acc[8][4];
#pragma unroll
  for (int i = 0; i < 8; ++i)
#pragma unroll
    for (int jj = 0; jj < 4; ++jj)
#pragma unroll
      for (int r = 0; r < 4; ++r) acc[i][jj][r] = 0.0f;

  {
    f16* dA0 = &lds[0];
    f16* dB0 = &lds[32768];
    f16* dA1 = &lds[8192];
    f16* dB1 = &lds[32768 + 8192];
    async16(&dA0[ldst0], A0 + gO0);       async16(&dA0[ldst1], A0 + gO1);
    async16(&dB0[ldst0], Bhi + gO0);      async16(&dB0[ldst1], Bhi + gO1);
    async16(&dA1[ldst0], A0 + 32 + gO0);  async16(&dA1[ldst1], A0 + 32 + gO1);
    async16(&dB1[ldst0], Bhi + 32 + gO0); async16(&dB1[ldst1], Bhi + 32 + gO1);
  }
  asm volatile("s_waitcnt vmcnt(4)" ::: "memory");
  __builtin_amdgcn_s_barrier();

  for (int t = 0; t < NT; ++t) {
    const int cur = t & 1, nxt = cur ^ 1;
    const bool st = (t + 1 < NT);
    const int kn = ((t + 1) & 15) * 64;
    const f16* An = A0 + kn;
    const f16* Bn = (((t + 1) & 16) ? Blo : Bhi) + kn;
    const f16* lA0 = &lds[(cur * 2 + 0) * 8192];
    const f16* lB0 = &lds[32768 + (cur * 2 + 0) * 8192];
    const f16* lA1 = &lds[(cur * 2 + 1) * 8192];
    const f16* lB1 = &lds[32768 + (cur * 2 + 1) * 8192];
    f16* sA0 = &lds[(nxt * 2 + 0) * 8192];
    f16* sB0 = &lds[32768 + (nxt * 2 + 0) * 8192];
    f16* sA1 = &lds[(nxt * 2 + 1) * 8192];
    f16* sB1 = &lds[32768 + (nxt * 2 + 1) * 8192];

    f16x8 a[4], b[4];

    // ---- phase 0: kh0, read a[0..3]+b[0..3] (8 reads); stage Ak0(t+1)
#pragma unroll
    for (int i = 0; i < 4; ++i) a[i] = *(const f16x8*)&lA0[offA[i]];
#pragma unroll
    for (int jj = 0; jj < 4; ++jj) b[jj] = *(const f16x8*)&lB0[offB[jj]];
    if (st) { async16(&sA0[ldst0], An + gO0); async16(&sA0[ldst1], An + gO1); }
    __builtin_amdgcn_s_barrier();
    __builtin_amdgcn_s_setprio(1);
#pragma unroll
    for (int i = 0; i < 4; ++i)
#pragma unroll
      for (int jj = 0; jj < 4; ++jj)
        acc[i][jj] = MFMA16(a[i], b[jj], acc[i][jj], 0, 0, 0);
    __builtin_amdgcn_s_setprio(0);
    __builtin_amdgcn_s_barrier();

    // ---- phase 1: kh0, read a[4..7] (4 reads, b reused); stage Bk0(t+1)
#pragma unroll
    for (int i = 0; i < 4; ++i) a[i] = *(const f16x8*)&lA0[offA[4 + i]];
    if (st) { async16(&sB0[ldst0], Bn + gO0); async16(&sB0[ldst1], Bn + gO1); }
    __builtin_amdgcn_s_barrier();
    __builtin_amdgcn_s_setprio(1);
#pragma unroll
    for (int i = 0; i < 4; ++i)
#pragma unroll
      for (int jj = 0; jj < 4; ++jj)
        acc[4 + i][jj] = MFMA16(a[i], b[jj], acc[4 + i][jj], 0, 0, 0);
    __builtin_amdgcn_s_setprio(0);
    if (t == NT - 1) {
      asm volatile("s_waitcnt vmcnt(0)" ::: "memory");
    } else {
      asm volatile("s_waitcnt vmcnt(4)" ::: "memory");  // Ak1,Bk1(t) landed
    }
    __builtin_amdgcn_s_barrier();

    // ---- phase 2: kh1, read a[0..3]+b[0..3]; stage Ak1(t+1)
#pragma unroll
    for (int i = 0; i < 4; ++i) a[i] = *(const f16x8*)&lA1[offA[i]];
#pragma unroll
    for (int jj = 0; jj < 4; ++jj) b[jj] = *(const f16x8*)&lB1[offB[jj]];
    if (st) { async16(&sA1[ldst0], An + 32 + gO0); async16(&sA1[ldst1], An + 32 + gO1); }
    __builtin_amdgcn_s_barrier();
    __builtin_amdgcn_s_setprio(1);
#pragma unroll
    for (int i = 0; i < 4; ++i)
#pragma unroll
      for (int jj = 0; jj < 4; ++jj)
        acc[i][jj] = MFMA16(a[i], b[jj], acc[i][jj], 0, 0, 0);
    __builtin_amdgcn_s_setprio(0);
    __builtin_amdgcn_s_barrier();

    // ---- phase 3: kh1, read a[4..7]; stage Bk1(t+1)
#pragma unroll
    for (int i = 0; i < 4; ++i) a[i] = *(const f16x8*)&lA1[offA[4 + i]];
    if (st) { async16(&sB1[ldst0], Bn + 32 + gO0); async16(&sB1[ldst1], Bn + 32 + gO1); }
    __builtin_amdgcn_s_barrier();
    __builtin_amdgcn_s_setprio(1);
#pragma unroll
    for (int i = 0; i < 4; ++i)
#pragma unroll
      for (int jj = 0; jj < 4; ++jj)
        acc[4 + i][jj] = MFMA16(a[i], b[jj], acc[4 + i][jj], 0, 0, 0);
    __builtin_amdgcn_s_setprio(0);
    asm volatile("s_waitcnt vmcnt(4)" ::: "memory");  // Ak0,Bk0(t+1) landed
    __builtin_amdgcn_s_barrier();
  }

  // -------------------- epilogue --------------------
  const int er0 = wm * 128 + qd * 4;
  const int ec0 = wn * 64 + frow;
  float bias[4];
#pragma unroll
  for (int jj = 0; jj < 4; ++jj) {
    const int c = colB0 + ec0 + jj * 16;
    bias[jj] = c < 1024 ? bq[c] : (c < 2048 ? bk[c - 1024] : bv[c - 2048]);
  }

  if (!ext) {
    if (colB0 < 1024) {  // q: hi+lo
#pragma unroll
      for (int jj = 0; jj < 4; ++jj) {
        const int c = colB0 + ec0 + jj * 16;
#pragma unroll
        for (int i = 0; i < 8; ++i)
#pragma unroll
          for (int r = 0; r < 4; ++r) {
            const int row = mrow0 + er0 + i * 16 + r;
            const float val = acc[i][jj][r] + bias[jj];
            const size_t idx = (size_t)row * HH + c;
            const f16 h = (f16)val;
            q_hi[idx] = h;
            q_lo[idx] = (f16)(val - (float)h);
          }
      }
    } else if (colB0 < 2048) {  // token k
#pragma unroll
      for (int jj = 0; jj < 4; ++jj) {
        const int c = colB0 + ec0 + jj * 16 - 1024;
#pragma unroll
        for (int i = 0; i < 8; ++i)
#pragma unroll
          for (int r = 0; r < 4; ++r) {
            const int row = mrow0 + er0 + i * 16 + r;
            kt[(size_t)row * HH + c] = (f16)(acc[i][jj][r] + bias[jj]);
          }
      }
    } else {  // token v
#pragma unroll
      for (int jj = 0; jj < 4; ++jj) {
        const int c = colB0 + ec0 + jj * 16 - 2048;
#pragma unroll
        for (int i = 0; i < 8; ++i)
#pragma unroll
          for (int r = 0; r < 4; ++r) {
            const int row = mrow0 + er0 + i * 16 + r;
            vt[(size_t)row * HH + c] = (f16)(acc[i][jj][r] + bias[jj]);
          }
      }
    }
  } else {
    if (colB0 < 2048) {  // ext k: hi+lo
#pragma unroll
      for (int jj = 0; jj < 4; ++jj) {
        const int c = colB0 + ec0 + jj * 16 - 1024;
#pragma unroll
        for (int i = 0; i < 8; ++i)
#pragma unroll
          for (int r = 0; r < 4; ++r) {
            const int row = mrow0 + er0 + i * 16 + r;
            const float val = acc[i][jj][r] + bias[jj];
            const size_t idx = (size_t)row * HH + c;
            const f16 h = (f16)val;
            ke_hi[idx] = h;
            ke_lo[idx] = (f16)(val - (float)h);
          }
      }
    } else {  // ext v -> veT[b][h][e], transposed via LDS in two h-halves
      f16* tl = lds;  // [128][264]
      const int b = mrow0 >> 9, e0 = mrow0 & 511;
      const int h0 = colB0 - 2048;
#pragma unroll
      for (int p = 0; p < 2; ++p) {
        __syncthreads();
        if ((wn >> 1) == p) {
          const int hL = (wn & 1) * 64 + frow;
#pragma unroll
          for (int jj = 0; jj < 4; ++jj)
#pragma unroll
            for (int i = 0; i < 8; ++i)
#pragma unroll
              for (int r = 0; r < 4; ++r) {
                const int e = er0 + i * 16 + r;
                tl[(hL + jj * 16) * 264 + e] = (f16)(acc[i][jj][r] + bias[jj]);
              }
        }
        __syncthreads();
        for (int c = tid; c < 128 * 32; c += 512) {
          const int hL = c >> 5, ch = c & 31;
          const f16x8 v = *(const f16x8*)&tl[hL * 264 + ch * 8];
          *(f16x8*)&veT[(size_t)(b * HH + h0 + p * 128 + hL) * EE + e0 + ch * 8] = v;
        }
      }
    }
  }
}

// ---------------------------------------------------------------------------
// Score GEMM (R11): tile widened 256x128 -> 128x256 (m x e) so q_hi/q_lo are
// read 2x instead of 4x (-64MB of re-read traffic); ke re-reads double but
// the 1MB/slice is L2/L3-resident. Same 144KB triple-buffer, same 6-loads/
// step counted-vmcnt ledger (Ah x1 + Al x1 + Bh x2 + Bl x2), same swizzle
// involution (row parity preserved: region row = c*128+srB, 128 % 4 == 0).
// 8 waves = 2m x 4n, each 64x64, acc[4][4]. Grid 2nt x 16mt x 8(b,kh) = 256.
// ---------------------------------------------------------------------------
__global__ __launch_bounds__(512, 1) void score_kernel(
    const f16* __restrict__ q_hi, const f16* __restrict__ q_lo,
    const f16* __restrict__ ke_hi, const f16* __restrict__ ke_lo,
    float* __restrict__ s_part) {
  const int b = blockIdx.z & 3;
  const int khalf = blockIdx.z >> 2;
  const int mtile = blockIdx.y;  // 0..15 (128 rows of s)
  const int ntile = blockIdx.x;  // 0..1  (256 cols of e)

  // per buffer: Ah 4096 | Al 4096 | Bh 8192 | Bl 8192 f16 = 48KB; x3 = 144KB
  __shared__ f16 lds[73728];

  const int tid = threadIdx.x;
  const int wave = tid >> 6, lane = tid & 63;
  const int wm = wave >> 2, wn = wave & 3;
  const int frow = lane & 15, qd = lane >> 4;

  const size_t aoff = ((size_t)b * SS + mtile * 128) * HH + khalf * 512;
  const size_t boff = ((size_t)b * EE + ntile * 256) * HH + khalf * 512;
  const f16* Ah = q_hi + aoff;
  const f16* Al = q_lo + aoff;
  const f16* Bh = ke_hi + boff;
  const f16* Bl = ke_lo + boff;

  const int srow = tid >> 2;                             // 0..127
  const int scol = ((tid & 3) ^ ((srow >> 1) & 3)) * 8;  // pre-swizzled src col
  const size_t gR0 = (size_t)srow * HH + scol;           // rows 0..127
  const size_t gR1 = (size_t)(128 + srow) * HH + scol;   // rows 128..255 (B only)
  const int ldst = (wave * 64) * 8;          // f16 units: = tid*8 per thread
  const int ldst1 = 4096 + (wave * 64) * 8;  // second 128-row half of B

  int offA[4], offB[4];
#pragma unroll
  for (int i = 0; i < 4; ++i) {
    const int r = wm * 64 + i * 16 + frow;   // 0..127
    offA[i] = r * 32 + ((qd ^ ((r >> 1) & 3)) * 8);
  }
#pragma unroll
  for (int jj = 0; jj < 4; ++jj) {
    const int r = wn * 64 + jj * 16 + frow;  // 0..255
    offB[jj] = r * 32 + ((qd ^ ((r >> 1) & 3)) * 8);
  }

  f32x4 acc[4][4];
#pragma unroll
  for (int i = 0; i < 4; ++i)
#pragma unroll
    for (int jj = 0; jj < 4; ++jj)
#pragma unroll
      for (int r = 0; r < 4; ++r) acc[i][jj][r] = 0.0f;

  // Prologue: stage step 0 -> buf0 and step 1 -> buf1 (6 loads each;
  // order Ah, Al, Bh x2, Bl x2)
#pragma unroll
  for (int p = 0; p < 2; ++p) {
    f16* dAh = &lds[p * 24576];
    f16* dAl = &lds[p * 24576 + 4096];
    f16* dBh = &lds[p * 24576 + 8192];
    f16* dBl = &lds[p * 24576 + 16384];
    const int ko = p * 32;
    async16(&dAh[ldst], Ah + ko + gR0);
    async16(&dAl[ldst], Al + ko + gR0);
    async16(&dBh[ldst], Bh + ko + gR0);  async16(&dBh[ldst1], Bh + ko + gR1);
    async16(&dBl[ldst], Bl + ko + gR0);  async16(&dBl[ldst1], Bl + ko + gR1);
  }
  asm volatile("s_waitcnt vmcnt(6)" ::: "memory");  // step 0's 6 landed
  __builtin_amdgcn_s_barrier();

  int cur = 0, stg = 2;
  for (int t = 0; t < 16; ++t) {
    const bool st = (t < 14);
    const int kk = (t + 2) * 32;
    const f16* lAh = &lds[cur * 24576];
    const f16* lAl = &lds[cur * 24576 + 4096];
    const f16* lBh = &lds[cur * 24576 + 8192];
    const f16* lBl = &lds[cur * 24576 + 16384];

    // stage step t+2 (6 loads) into buf stg — last read ended 2 barriers ago
    if (st) {
      f16* sAh = &lds[stg * 24576];
      f16* sAl = &lds[stg * 24576 + 4096];
      f16* sBh = &lds[stg * 24576 + 8192];
      f16* sBl = &lds[stg * 24576 + 16384];
      async16(&sAh[ldst], Ah + kk + gR0);
      async16(&sAl[ldst], Al + kk + gR0);
      async16(&sBh[ldst], Bh + kk + gR0);  async16(&sBh[ldst1], Bh + kk + gR1);
      async16(&sBl[ldst], Bl + kk + gR0);  async16(&sBl[ldst1], Bl + kk + gR1);
    }

    f16x8 ah[4], bh[4], bl[4], al[4];
#pragma unroll
    for (int i = 0; i < 4; ++i) ah[i] = *(const f16x8*)&lAh[offA[i]];
#pragma unroll
    for (int jj = 0; jj < 4; ++jj) bh[jj] = *(const f16x8*)&lBh[offB[jj]];
#pragma unroll
    for (int jj = 0; jj < 4; ++jj) bl[jj] = *(const f16x8*)&lBl[offB[jj]];
#pragma unroll
    for (int i = 0; i < 4; ++i) al[i] = *(const f16x8*)&lAl[offA[i]];

    __builtin_amdgcn_s_setprio(1);
#pragma unroll
    for (int i = 0; i < 4; ++i)
#pragma unroll
      for (int jj = 0; jj < 4; ++jj) {
        acc[i][jj] = MFMA16(ah[i], bh[jj], acc[i][jj], 0, 0, 0);
        acc[i][jj] = MFMA16(ah[i], bl[jj], acc[i][jj], 0, 0, 0);
        acc[i][jj] = MFMA16(al[i], bh[jj], acc[i][jj], 0, 0, 0);
      }
    __builtin_amdgcn_s_setprio(0);

    if (st) { asm volatile("s_waitcnt vmcnt(6)" ::: "memory"); }  // t+1 landed
    else    { asm volatile("s_waitcnt vmcnt(0)" ::: "memory"); }
    __builtin_amdgcn_s_barrier();

    cur = (cur == 2) ? 0 : cur + 1;
    stg = (stg == 2) ? 0 : stg + 1;
  }

  // epilogue: scalar f32 stores
  float* dst = s_part + (size_t)khalf * BB * SS * EE + (size_t)b * SS * EE;
#pragma unroll
  for (int jj = 0; jj < 4; ++jj) {
    const int e = ntile * 256 + wn * 64 + jj * 16 + frow;
#pragma unroll
    for (int i = 0; i < 4; ++i)
#pragma unroll
      for (int r = 0; r < 4; ++r) {
        const int s = mtile * 128 + wm * 64 + i * 16 + qd * 4 + r;
        dst[(size_t)s * EE + e] = acc[i][jj][r];
      }
  }
}

// Fused selfdot + softmax (unchanged)
__global__ __launch_bounds__(256) void softmax_kernel(
    const f16* __restrict__ q_hi, const f16* __restrict__ q_lo,
    const f16* __restrict__ kt, const float* __restrict__ s_part,
    f16* __restrict__ probs, float* __restrict__ p_self) {
  const int t = blockIdx.x * 4 + (threadIdx.x >> 6);
  const int lane = threadIdx.x & 63;

  const size_t base = (size_t)t * HH;
  float ss = 0.f;
#pragma unroll
  for (int it = 0; it < 4; ++it) {
    const int off = it * 256 + lane * 4;
    const f16x4 qh = *(const f16x4*)&q_hi[base + off];
    const f16x4 ql = *(const f16x4*)&q_lo[base + off];
    const f16x4 kh = *(const f16x4*)&kt[base + off];
    ss += ((float)qh.x + (float)ql.x) * (float)kh.x;
    ss += ((float)qh.y + (float)ql.y) * (float)kh.y;
    ss += ((float)qh.z + (float)ql.z) * (float)kh.z;
    ss += ((float)qh.w + (float)ql.w) * (float)kh.w;
  }
#pragma unroll
  for (int m = 32; m > 0; m >>= 1) ss += __shfl_xor(ss, m, 64);

  const float* r0 = s_part + (size_t)t * EE;
  const float* r1 = s_part + (size_t)BB * SS * EE + (size_t)t * EE;
  const float4 a0 = *(const float4*)&r0[lane * 4];
  const float4 a1 = *(const float4*)&r0[256 + lane * 4];
  const float4 c0 = *(const float4*)&r1[lane * 4];
  const float4 c1 = *(const float4*)&r1[256 + lane * 4];
  const float v0x = a0.x + c0.x, v0y = a0.y + c0.y, v0z = a0.z + c0.z, v0w = a0.w + c0.w;
  const float v1x = a1.x + c1.x, v1y = a1.y + c1.y, v1z = a1.z + c1.z, v1w = a1.w + c1.w;
  float m = fmaxf(fmaxf(fmaxf(v0x, v0y), fmaxf(v0z, v0w)),
                  fmaxf(fmaxf(v1x, v1y), fmaxf(v1z, v1w)));
#pragma unroll
  for (int sh = 32; sh > 0; sh >>= 1) m = fmaxf(m, __shfl_xor(m, sh, 64));
  m = fmaxf(m, ss);
  const float e0 = __expf(v0x - m), e1 = __expf(v0y - m);
  const float e2 = __expf(v0z - m), e3 = __expf(v0w - m);
  const float e4 = __expf(v1x - m), e5 = __expf(v1y - m);
  const float e6 = __expf(v1z - m), e7 = __expf(v1w - m);
  float sum = ((e0 + e1) + (e2 + e3)) + ((e4 + e5) + (e6 + e7));
#pragma unroll
  for (int sh = 32; sh > 0; sh >>= 1) sum += __shfl_xor(sum, sh, 64);
  const float es = __expf(ss - m);
  const float inv = 1.0f / (sum + es);
  f16x4 p0, p1;
  p0.x = (f16)(e0 * inv); p0.y = (f16)(e1 * inv);
  p0.z = (f16)(e2 * inv); p0.w = (f16)(e3 * inv);
  p1.x = (f16)(e4 * inv); p1.y = (f16)(e5 * inv);
  p1.z = (f16)(e6 * inv); p1.w = (f16)(e7 * inv);
  *(f16x4*)&probs[(size_t)t * EE + lane * 4] = p0;
  *(f16x4*)&probs[(size_t)t * EE + 256 + lane * 4] = p1;
  if (lane == 0) p_self[t] = es * inv;
}

// ---------------------------------------------------------------------------
// PV GEMM (R7 1-barrier version): 256x128, K=512, triple-buffer depth-2,
// one barrier + counted vmcnt per k-step.
// ---------------------------------------------------------------------------
__global__ __launch_bounds__(512, 2) void pv_kernel(
    const f16* __restrict__ probs, const f16* __restrict__ veT,
    const float* __restrict__ p_self, const f16* __restrict__ vt,
    float* __restrict__ out) {
  const int b = blockIdx.z;
  const int mtile = blockIdx.y;  // 0..7 (256 rows of s)
  const int ntile = blockIdx.x;  // 0..7 (128 cols of h)

  __shared__ f16 lds[36864];  // 72 KB: 3 x (A 8192 | B 4096)

  const int tid = threadIdx.x;
  const int wave = tid >> 6, lane = tid & 63;
  const int wm = wave >> 1, wn = wave & 1;
  const int frow = lane & 15, qd = lane >> 4;

  const size_t aoff = ((size_t)b * SS + mtile * 256) * EE;
  const size_t boff = ((size_t)b * HH + ntile * 128) * EE;
  const f16* A = probs + aoff;
  const f16* Bv = veT + boff;

  const int srow = tid >> 2;
  const int scol = ((tid & 3) ^ ((srow >> 1) & 3)) * 8;
  const size_t gA0 = (size_t)srow * EE + scol;
  const size_t gA1 = (size_t)(128 + srow) * EE + scol;
  const int ldstA0 = (wave * 64) * 8;
  const int ldstA1 = (512 + wave * 64) * 8;
  const int ldstB0 = (wave * 64) * 8;

  int offA[4], offB[4];
#pragma unroll
  for (int i = 0; i < 4; ++i) {
    const int r = wm * 64 + i * 16 + frow;
    offA[i] = r * 32 + ((qd ^ ((r >> 1) & 3)) * 8);
  }
#pragma unroll
  for (int jj = 0; jj < 4; ++jj) {
    const int r = wn * 64 + jj * 16 + frow;
    offB[jj] = r * 32 + ((qd ^ ((r >> 1) & 3)) * 8);
  }

  f32x4 acc[4][4];
#pragma unroll
  for (int i = 0; i < 4; ++i)
#pragma unroll
    for (int jj = 0; jj < 4; ++jj)
#pragma unroll
      for (int r = 0; r < 4; ++r) acc[i][jj][r] = 0.0f;

  {
    f16* dA0 = &lds[0], *dB0 = &lds[8192];
    f16* dA1 = &lds[12288], *dB1 = &lds[12288 + 8192];
    async16(&dA0[ldstA0], A + gA0); async16(&dA0[ldstA1], A + gA1);
    async16(&dB0[ldstB0], Bv + gA0);
    async16(&dA1[ldstA0], A + 32 + gA0); async16(&dA1[ldstA1], A + 32 + gA1);
    async16(&dB1[ldstB0], Bv + 32 + gA0);
  }
  asm volatile("s_waitcnt vmcnt(3)" ::: "memory");
  __builtin_amdgcn_s_barrier();

  int cur = 0, stg = 2;
  for (int t = 0; t < 16; ++t) {
    const bool st = (t < 14);
    const int kk = (t + 2) * 32;
    const f16* lA = &lds[cur * 12288];
    const f16* lB = &lds[cur * 12288 + 8192];

    if (st) {
      f16* sA = &lds[stg * 12288];
      f16* sB = &lds[stg * 12288 + 8192];
      async16(&sA[ldstA0], A + kk + gA0); async16(&sA[ldstA1], A + kk + gA1);
      async16(&sB[ldstB0], Bv + kk + gA0);
    }

    f16x8 a[4], bb[4];
#pragma unroll
    for (int i = 0; i < 4; ++i) a[i] = *(const f16x8*)&lA[offA[i]];
#pragma unroll
    for (int jj = 0; jj < 4; ++jj) bb[jj] = *(const f16x8*)&lB[offB[jj]];

    __builtin_amdgcn_s_setprio(1);
#pragma unroll
    for (int i = 0; i < 4; ++i)
#pragma unroll
      for (int jj = 0; jj < 4; ++jj)
        acc[i][jj] = MFMA16(a[i], bb[jj], acc[i][jj], 0, 0, 0);
    __builtin_amdgcn_s_setprio(0);

    if (st) { asm volatile("s_waitcnt vmcnt(3)" ::: "memory"); }
    else    { asm volatile("s_waitcnt vmcnt(0)" ::: "memory"); }
    __builtin_amdgcn_s_barrier();

    cur = (cur == 2) ? 0 : cur + 1;
    stg = (stg == 2) ? 0 : stg + 1;
  }

  // epilogue
#pragma unroll
  for (int jj = 0; jj < 4; ++jj) {
    const int h = ntile * 128 + wn * 64 + jj * 16 + frow;
#pragma unroll
    for (int i = 0; i < 4; ++i)
#pragma unroll
      for (int r = 0; r < 4; ++r) {
        const int s = mtile * 256 + wm * 64 + i * 16 + qd * 4 + r;
        const size_t t = (size_t)b * SS + s;
        __builtin_nontemporal_store(
            acc[i][jj][r] + p_self[t] * (float)vt[t * HH + h], &out[t * HH + h]);
      }
  }
}

extern "C" void kernel_launch(void* const* d_in, const int* in_sizes, int n_in,
                              void* d_out, int out_size, void* d_ws, size_t ws_size,
                              hipStream_t stream) {
  const float* hidden = (const float*)d_in[0];
  const float* ext    = (const float*)d_in[1];
  const float* Wq = (const float*)d_in[2];
  const float* bq = (const float*)d_in[3];
  const float* Wk = (const float*)d_in[4];
  const float* bk = (const float*)d_in[5];
  const float* Wv = (const float*)d_in[6];
  const float* bv = (const float*)d_in[7];
  float* out = (float*)d_out;

  char* ws = (char*)d_ws;
  size_t off = 0;
  auto alloc = [&](size_t bytes) {
    char* p = ws + off;
    off += (bytes + 255) & ~(size_t)255;
    return p;
  };
  const size_t TOK = 8192, EXT = 2048;
  f16* xh    = (f16*)alloc(TOK * HH * 2);
  f16* xe    = (f16*)alloc(EXT * HH * 2);
  f16* wt_hi = (f16*)alloc(3072ull * HH * 2);
  f16* wt_lo = (f16*)alloc(3072ull * HH * 2);
  f16* q_hi  = (f16*)alloc(TOK * HH * 2);
  f16* q_lo  = (f16*)alloc(TOK * HH * 2);
  f16* kt    = (f16*)alloc(TOK * HH * 2);
  f16* vt    = (f16*)alloc(TOK * HH * 2);
  f16* ke_hi = (f16*)alloc(EXT * HH * 2);
  f16* ke_lo = (f16*)alloc(EXT * HH * 2);
  f16* veT   = (f16*)alloc((size_t)BB * HH * EE * 2);
  float* p_self = (float*)alloc(TOK * 4);
  float* s_part = (float*)alloc(2ull * BB * SS * EE * 4);
  f16* probs    = (f16*)alloc((size_t)BB * SS * EE * 2);

  // 1. merged prep: cast + W transpose/split in one launch
  prep_kernel<<<13312, 256, 0, stream>>>(hidden, ext, Wq, Wk, Wv,
                                         xh, xe, wt_hi, wt_lo);

  // 2. fused projection GEMM, 256^2, balanced 8/4-read phases (R10)
  proj_kernel<<<448, 512, 0, stream>>>(
      xh, xe, wt_hi, wt_lo, bq, bk, bv,
      q_hi, q_lo, kt, vt, ke_hi, ke_lo, veT);

  // 3. attention (score now 128x256 wide-tile: q read 2x instead of 4x)
  score_kernel<<<dim3(2, 16, 8), 512, 0, stream>>>(q_hi, q_lo, ke_hi, ke_lo, s_part);
  softmax_kernel<<<2048, 256, 0, stream>>>(q_hi, q_lo, kt, s_part, probs, p_self);
  pv_kernel<<<dim3(8, 8, 4), 512, 0, stream>>>(probs, veT, p_self, vt, out);
}